// Round 4
// baseline (537.499 us; speedup 1.0000x reference)
//
#include <hip/hip_runtime.h>

// Prop3D: x (8, 4, 512, 64) f32 -> (map_hidden, map_mask), each (8, 512, 4, 64, 65) f32.
// For rel in 0..3 (base b = 1<<rel):
//   valid (s,e): s%b==0, e<64, (e-s)%b==0, e-s>=b
//   hidden[bi,d,rel,s,e] = max(x[bi,rel,d, s .. s+k-1]), k=(e-s)>>rel   (contiguous window!)
//   mask  [..same..]     = 1.0
// Everything else is 0. Output is hidden ++ mask, flat.
//
// R4 = R3's algorithm (decode hoisted once per thread, persistent 2048-block grid,
// pure-stream mask phase) with the crash-suspect constructs removed:
//   - no runtime-indexed local arrays (x row loaded from global per region)
//   - aw[][] fully initialized for all threads
//   - single-buffer sparse table, two barriers per region (16 total/block)

#define HIDDEN_ELEMS 68157440LL   // 8*512*4*64*65

typedef float vfloat4 __attribute__((ext_vector_type(4)));

__global__ __launch_bounds__(256) void prop3d_kernel(const float* __restrict__ x,
                                                     float* __restrict__ out) {
    const int t   = threadIdx.x;
    const int b   = blockIdx.x;        // 0..2047
    const int rel = b & 3;
    const int j0  = (b >> 2) * 8;      // first k (= bi*512 + d) of this block's 8
    const int bmask = (1 << rel) - 1;

    // ---------- per-thread gid-invariant decode (done ONCE) ----------
    // Element f = (t + j*256)*4 + u, j = 0..4; f < 4160 (64*65) is the tail guard.
    // aw[j][u] = addr1 | (addr2<<16) (word indices into ST); vmask bit (j*4+u) = valid.
    int aw[5][4];
    unsigned vmask = 0;
    #pragma unroll
    for (int j = 0; j < 5; ++j) {
        #pragma unroll
        for (int u = 0; u < 4; ++u) {
            const int f = (t + j * 256) * 4 + u;
            int w = 0;
            if (f < 4160) {
                const int s = f / 65;          // magic-mul div
                const int e = f - s * 65;      // 0..64
                const int diff = e - s;
                const bool valid = (e < 64) & (diff > 0) &
                                   ((s & bmask) == 0) & ((diff & bmask) == 0);
                const int k  = diff >> rel;        // window length when valid (>=1)
                const int kk = valid ? k : 1;      // clamp for safe LDS reads
                const int p  = 31 - __clz(kk);     // floor(log2(kk)), 0..5
                const int a1 = s * 6 + p;
                const int a2 = (s + kk - (1 << p)) * 6 + p;
                w = a1 | (a2 << 16);
                vmask |= (valid ? 1u : 0u) << (j * 4 + u);
            }
            aw[j][u] = w;
        }
    }

    // Sparse table: ST[s][p] = max(x[s .. s+2^p-1]) (clamped; clamped entries are
    // never consumed by valid queries).
    __shared__ float ST[64][6];
    const float* __restrict__ stb = &ST[0][0];

    // This block's 8 x-rows are consecutive (512 % 8 == 0 keeps them in one bi).
    const int bi = j0 >> 9;
    const int d0 = j0 & 511;
    const float* __restrict__ xbase = x + (((long long)(bi * 4 + rel)) * 512 + d0) * 64;

    // ---------- hidden phase: 8 regions ----------
    for (int r = 0; r < 8; ++r) {
        __syncthreads();               // previous region's ST reads complete
        if (t < 64) {
            float v = xbase[r * 64 + t];
            ST[t][0] = v;
            #pragma unroll
            for (int p = 1; p < 6; ++p) {
                int jj = t + (1 << (p - 1));
                jj = jj > 63 ? 63 : jj;
                float o = __shfl(v, jj, 64);   // lane jj's level-(p-1) value
                v = fmaxf(v, o);
                ST[t][p] = v;
            }
        }
        __syncthreads();               // build(r) visible to all

        const long long gid = (long long)(j0 + r) * 4 + rel;
        vfloat4* __restrict__ outH = reinterpret_cast<vfloat4*>(out) + gid * 1040;
        #pragma unroll
        for (int j = 0; j < 5; ++j) {
            const int idx = t + j * 256;
            if (idx < 1040) {
                vfloat4 v;
                #pragma unroll
                for (int u = 0; u < 4; ++u) {
                    const int w = aw[j][u];
                    const float a = stb[w & 0xffff];
                    const float c = stb[w >> 16];
                    const float m = fmaxf(a, c);
                    v[u] = ((vmask >> (j * 4 + u)) & 1) ? m : 0.0f;
                }
                outH[idx] = v;
            }
        }
    }

    // ---------- mask phase: pure store stream (pattern in registers) ----------
    vfloat4 mpat[5];
    #pragma unroll
    for (int j = 0; j < 5; ++j) {
        #pragma unroll
        for (int u = 0; u < 4; ++u)
            mpat[j][u] = ((vmask >> (j * 4 + u)) & 1) ? 1.0f : 0.0f;
    }
    #pragma unroll
    for (int r = 0; r < 8; ++r) {
        const long long gid = (long long)(j0 + r) * 4 + rel;
        vfloat4* __restrict__ outM =
            reinterpret_cast<vfloat4*>(out + HIDDEN_ELEMS) + gid * 1040;
        #pragma unroll
        for (int j = 0; j < 5; ++j) {
            const int idx = t + j * 256;
            if (idx < 1040) outM[idx] = mpat[j];
        }
    }
}

extern "C" void kernel_launch(void* const* d_in, const int* in_sizes, int n_in,
                              void* d_out, int out_size, void* d_ws, size_t ws_size,
                              hipStream_t stream) {
    const float* x = (const float*)d_in[0];
    float* out = (float*)d_out;
    // 2048 persistent blocks: (rel, 8-region chunk of k = bi*512+d)
    prop3d_kernel<<<2048, 256, 0, stream>>>(x, out);
}